// Round 1
// baseline (441.228 us; speedup 1.0000x reference)
//
#include <hip/hip_runtime.h>

#define N_BINS 10
#define EPS 1e-7f

typedef unsigned int uint;

// ---------------------------------------------------------------------------
// ws layout (uint): [0..9] counts, [10..19] correct
// ---------------------------------------------------------------------------

__global__ void zero_ws_kernel(uint* ws) {
    if (threadIdx.x < 2 * N_BINS) ws[threadIdx.x] = 0u;
}

__device__ __forceinline__ void process_row(const float v[10], int label,
                                            uint& c8, uint& k8, uint& c9, uint& k9,
                                            uint* scount, uint* scorrect) {
    // sm = logits - EPS, per element (faithful to reference)
    float m = v[0] - EPS;
    int am = 0;
#pragma unroll
    for (int j = 1; j < 10; ++j) {
        float s = v[j] - EPS;
        if (s > m) { m = s; am = j; }   // strict > keeps FIRST max (jnp.argmax)
    }
    int acc = (am == label) ? 1 : 0;

    // searchsorted(boundaries, conf, side=left) - 1 == (#boundaries < conf) - 1
    int idx = 0;
#pragma unroll
    for (int j = 0; j <= 10; ++j) {
        idx += ((0.1f * (float)j) < m) ? 1 : 0;
    }
    int bin = idx - 1;

    if (bin == 9)      { c9++; k9 += acc; }          // ~65% of rows
    else if (bin == 8) { c8++; k8 += acc; }          // ~13% of rows
    else if (bin >= 0 && bin < 8) {                  // rare path
        atomicAdd(&scount[bin], 1u);
        if (acc) atomicAdd(&scorrect[bin], 1u);
    }
    // bin < 0 (conf <= 0) or bin >= 10: overflow segment, dropped
}

__global__ void __launch_bounds__(512)
hist_kernel(const float* __restrict__ logits, const int* __restrict__ labels,
            uint* __restrict__ ws, int npairs, int n_rows) {
    __shared__ uint scount[N_BINS];
    __shared__ uint scorrect[N_BINS];
    if (threadIdx.x < N_BINS) { scount[threadIdx.x] = 0u; scorrect[threadIdx.x] = 0u; }
    __syncthreads();

    uint c8 = 0, k8 = 0, c9 = 0, k9 = 0;

    const int stride = gridDim.x * blockDim.x;
    const int tid0   = blockIdx.x * blockDim.x + threadIdx.x;

    for (int p = tid0; p < npairs; p += stride) {
        const float4* lp = reinterpret_cast<const float4*>(logits) + (size_t)p * 5;
        float4 q0 = lp[0], q1 = lp[1], q2 = lp[2], q3 = lp[3], q4 = lp[4];
        int2 lab = reinterpret_cast<const int2*>(labels)[p];

        float a[10] = { q0.x, q0.y, q0.z, q0.w, q1.x, q1.y, q1.z, q1.w, q2.x, q2.y };
        float b[10] = { q2.z, q2.w, q3.x, q3.y, q3.z, q3.w, q4.x, q4.y, q4.z, q4.w };

        process_row(a, lab.x, c8, k8, c9, k9, scount, scorrect);
        process_row(b, lab.y, c8, k8, c9, k9, scount, scorrect);
    }

    // odd-N tail row (not hit for the 8M bench, kept for generality)
    if ((n_rows & 1) && tid0 == 0) {
        const float* rp = logits + (size_t)(n_rows - 1) * 10;
        float t[10];
#pragma unroll
        for (int j = 0; j < 10; ++j) t[j] = rp[j];
        process_row(t, labels[n_rows - 1], c8, k8, c9, k9, scount, scorrect);
    }

    // wave-level reduction of the hot-bin register accumulators
#pragma unroll
    for (int off = 32; off > 0; off >>= 1) {
        c8 += __shfl_down(c8, off);
        k8 += __shfl_down(k8, off);
        c9 += __shfl_down(c9, off);
        k9 += __shfl_down(k9, off);
    }
    if ((threadIdx.x & 63) == 0) {
        atomicAdd(&scount[8], c8);
        atomicAdd(&scorrect[8], k8);
        atomicAdd(&scount[9], c9);
        atomicAdd(&scorrect[9], k9);
    }
    __syncthreads();

    if (threadIdx.x < N_BINS) {
        atomicAdd(&ws[threadIdx.x], scount[threadIdx.x]);
        atomicAdd(&ws[N_BINS + threadIdx.x], scorrect[threadIdx.x]);
    }
}

__global__ void finalize_kernel(const uint* __restrict__ ws, float* __restrict__ out) {
    if (threadIdx.x < N_BINS) {
        uint c = ws[threadIdx.x];
        uint k = ws[N_BINS + threadIdx.x];
        out[threadIdx.x] = (c > 0u) ? ((float)k / (float)c) : 0.0f;
    }
}

extern "C" void kernel_launch(void* const* d_in, const int* in_sizes, int n_in,
                              void* d_out, int out_size, void* d_ws, size_t ws_size,
                              hipStream_t stream) {
    const float* logits = (const float*)d_in[0];
    const int*   labels = (const int*)d_in[1];
    float*       out    = (float*)d_out;
    uint*        ws     = (uint*)d_ws;

    const int n_rows = in_sizes[1];          // N = 8,000,000
    const int npairs = n_rows / 2;

    zero_ws_kernel<<<1, 64, 0, stream>>>(ws);

    const int threads = 512;
    int blocks = (npairs + threads - 1) / threads;
    if (blocks > 1024) blocks = 1024;
    if (blocks < 1) blocks = 1;
    hist_kernel<<<blocks, threads, 0, stream>>>(logits, labels, ws, npairs, n_rows);

    finalize_kernel<<<1, 64, 0, stream>>>(ws, out);
}